// Round 13
// baseline (95.200 us; speedup 1.0000x reference)
//
#include <hip/hip_runtime.h>

#define VOCAB 4096
#define SLICES 8
#define SLICE 512            // codes per slice (8-way split per point-set)
#define GRP 8                // codes per max-tree group
#define NGRP (SLICE / GRP)   // 64 groups per slice
#define P 4                  // points per lane
#define PTS (64 * P)         // 256 points per block

// Empty-asm register barrier: forces the value into a VGPR, preventing
// fma-contraction / reassociation across it. Emits no instruction.
__device__ __forceinline__ float opaque(float x) {
  asm volatile("" : "+v"(x));
  return x;
}

// v_max3_f32: value-identical to nested fmaxf for finite inputs (max is
// exact). Compiler won't form max3 without nnan, so emit directly.
__device__ __forceinline__ float max3f(float a, float b, float c) {
  float d;
  asm("v_max3_f32 %0, %1, %2, %3" : "=v"(d) : "v"(a), "v"(b), "v"(c));
  return d;
}

// Prep: pack per-code {e0, e1, e2, h} where h = -0.5f*c and
// c = ((e0*e0+e1*e1)+e2*e2) rounded exactly like numpy (each product/sum
// individually rounded f32). h is an exact scale of c (exponent shift),
// so c = -2*h is recoverable bit-exactly. (Validated R10/R12: absmax 0.0.)
__global__ __launch_bounds__(256) void vq_prep_kernel(
    const float* __restrict__ cb, float4* __restrict__ cw,
    float* __restrict__ loss_slot) {
  int j = blockIdx.x * 256 + threadIdx.x;
  if (j == 0) *loss_slot = 0.0f;
  if (j < VOCAB) {
    float e0 = cb[3 * j + 0];
    float e1 = cb[3 * j + 1];
    float e2 = cb[3 * j + 2];
    float p0 = opaque(e0 * e0);
    float p1 = opaque(e1 * e1);
    float p2 = opaque(e2 * e2);
    float c = opaque(opaque(p0 + p1) + p2);
    cw[j] = make_float4(e0, e1, e2, -0.5f * c);
  }
}

// Surrogate scan value: t = x.e - c/2 (3 fma). Exact relation: a - 2T = D.
__device__ __forceinline__ float tval(float x0, float x1, float x2,
                                      float4 cd) {
  return fmaf(x0, cd.x, fmaf(x1, cd.y, fmaf(x2, cd.z, cd.w)));
}

// Bit-exact numpy f32 distance (validated absmax=0.0 R10/R12):
//   m = x.e (fma ascending k, first term single-rounded mul)
//   d = (a - 2m) + c;  c = -2*h exact (fma-contract-safe).
__device__ __forceinline__ float dist_f32(float x0, float x1, float x2,
                                          float a, float4 cd) {
  float m = fmaf(x2, cd.z, fmaf(x1, cd.y, x0 * cd.x));
  return fmaf(-2.0f, m, a) + (-2.0f * cd.w);
}

// Main: 256 blocks x 512 threads; block = 256 points (4/lane) x 8 slices.
// Codebook in LDS; surrogate scan; margin-certified 8-code exact rescan;
// bounded cooperative bit-exact fallback. ~93 KB LDS -> 1 block/CU.
__global__ __launch_bounds__(512) void vq_kernel(
    const float* __restrict__ feats, const float4* __restrict__ cw,
    float* __restrict__ out_quant, float* __restrict__ out_idx,
    float* __restrict__ out_loss, int npts) {
  __shared__ float4 sTab[VOCAB];            // 64 KB staged codebook
  __shared__ float sT1[SLICES * PTS];       // 8 KB per-slice best t
  __shared__ float sT2[SLICES * PTS];       // 8 KB per-slice 2nd-best
  __shared__ int sG[SLICES * PTS];          // 8 KB per-slice group base
  __shared__ unsigned long long sSlot[PTS]; // 2 KB fallback (d,idx) keys
  __shared__ int sList[PTS];                // 1 KB flagged point ids
  __shared__ int sCount;
  __shared__ double sL[PTS];                // 2 KB loss partials

  const int tid = threadIdx.x;
  const int lane = tid & 63;
  const int s = tid >> 6;                   // slice id (wave-uniform)

  if (tid == 0) sCount = 0;

  // Stage codebook: coalesced float4 copy, 8 per thread.
#pragma unroll
  for (int k = 0; k < VOCAB / 512; ++k) sTab[tid + k * 512] = cw[tid + k * 512];

  const int pbase = blockIdx.x * PTS;
  // Lane's P points: pbase + k*64 + lane, k = 0..P-1.
  float px[P], py[P], pz[P], nn[P];
#pragma unroll
  for (int k = 0; k < P; ++k) {
    const int p = pbase + k * 64 + lane;
    px[k] = feats[3 * p + 0];
    py[k] = feats[3 * p + 1];
    pz[k] = feats[3 * p + 2];
    // ||x||^2 exactly as numpy: products rounded, then ((p0+p1)+p2)
    float q0 = opaque(px[k] * px[k]);
    float q1 = opaque(py[k] * py[k]);
    float q2 = opaque(pz[k] * pz[k]);
    nn[k] = opaque(opaque(q0 + q1) + q2);
  }

  __syncthreads();  // staging complete

  const float4* cs = sTab + s * SLICE;

  // Phase 1: surrogate max-scan, P points per lane, codes via LDS broadcast.
  float t1[P], t2[P];
  int gg[P];
#pragma unroll
  for (int k = 0; k < P; ++k) { t1[k] = -3.4e38f; t2[k] = -3.4e38f; gg[k] = 0; }
  for (int g = 0; g < NGRP; ++g) {
    const float4* gp = cs + g * GRP;  // same addr all lanes -> broadcast
    float4 c0 = gp[0], c1 = gp[1], c2 = gp[2], c3 = gp[3];
    float4 c4 = gp[4], c5 = gp[5], c6 = gp[6], c7 = gp[7];
#pragma unroll
    for (int k = 0; k < P; ++k) {
      float u0 = tval(px[k], py[k], pz[k], c0);
      float u1 = tval(px[k], py[k], pz[k], c1);
      float u2 = tval(px[k], py[k], pz[k], c2);
      float u3 = tval(px[k], py[k], pz[k], c3);
      float u4 = tval(px[k], py[k], pz[k], c4);
      float u5 = tval(px[k], py[k], pz[k], c5);
      float u6 = tval(px[k], py[k], pz[k], c6);
      float u7 = tval(px[k], py[k], pz[k], c7);
      float gm = max3f(max3f(u0, u1, u2), max3f(u3, u4, u5), fmaxf(u6, u7));
      t2[k] = fmaxf(t2[k], fminf(t1[k], gm));  // streaming top-2
      if (gm > t1[k]) gg[k] = g;               // strict >: earliest group
      t1[k] = fmaxf(t1[k], gm);
    }
  }
#pragma unroll
  for (int k = 0; k < P; ++k) {
    sT1[s * PTS + k * 64 + lane] = t1[k];
    sT2[s * PTS + k * 64 + lane] = t2[k];
    sG[s * PTS + k * 64 + lane] = s * SLICE + gg[k] * GRP;
  }
  __syncthreads();

  // Epilogue combine: tid < 256 owns block-point pt == tid. Thread (wave s,
  // lane l) owns point s*64+l == its OWN registers' point k = s.
  int bi = 0;
  float q0 = 0.0f, q1 = 0.0f, q2 = 0.0f;
  bool flagged = false;
  float x0 = px[0], x1 = py[0], x2 = pz[0], a = nn[0];
#pragma unroll
  for (int k = 1; k < P; ++k) {
    if (s == k) { x0 = px[k]; x1 = py[k]; x2 = pz[k]; a = nn[k]; }
  }
  if (tid < PTS) {
    float b1 = sT1[tid], b2 = sT2[tid];
    int gbase = sG[tid];
#pragma unroll
    for (int k = 1; k < SLICES; ++k) {  // ascending slice order
      float u1 = sT1[k * PTS + tid];
      float u2 = sT2[k * PTS + tid];
      b2 = fmaxf(fmaxf(b2, u2), fminf(b1, u1));
      if (u1 > b1) gbase = sG[k * PTS + tid];
      b1 = fmaxf(b1, u1);
    }
    // Margin test (validated R10/R12): if best group's t beats every other
    // group's max by more than worst-case surrogate-vs-numpy skew, ref
    // argmin is inside gbase. eps = a*2^-21 + 2^-20 (2x safe).
    float eps = fmaf(a, 0x1p-21f, 0x1p-20f);
    flagged = !((b1 - b2) > eps);
    if (flagged) {
      int pos = atomicAdd(&sCount, 1);
      sList[pos] = tid;
      sSlot[tid] = ~0ULL;
    } else {
      // Bit-exact rescan of the certified 8-code group; ascending, strict
      // <: np.argmin first-occurrence.
      float bd = 3.4e38f;
#pragma unroll
      for (int k = 0; k < GRP; ++k) {
        float4 cd = cw[gbase + k];
        float d = dist_f32(x0, x1, x2, a, cd);
        if (d < bd) { bd = d; bi = gbase + k; q0 = cd.x; q1 = cd.y; q2 = cd.z; }
      }
    }
  }
  __syncthreads();

  // Phase 2: cooperative bit-exact full rescan for flagged points.
  // 512 threads x 8 codes each; sortable (d,idx) key min-reduce: min key ==
  // min d, tie -> min idx (first occurrence).
  const int cnt = sCount;
  for (int f = 0; f < cnt; ++f) {
    const int fpt = sList[f];
    const int fp = pbase + fpt;
    float y0 = feats[3 * fp + 0];   // same addr all threads -> broadcast
    float y1 = feats[3 * fp + 1];
    float y2 = feats[3 * fp + 2];
    float yp0 = opaque(y0 * y0);
    float yp1 = opaque(y1 * y1);
    float yp2 = opaque(y2 * y2);
    float ay = opaque(opaque(yp0 + yp1) + yp2);
    float bd = 3.4e38f;
    int bj = 0;
#pragma unroll
    for (int k = 0; k < 8; ++k) {
      float4 cd = cw[tid * 8 + k];
      float d = dist_f32(y0, y1, y2, ay, cd);
      if (d < bd) { bd = d; bj = tid * 8 + k; }
    }
    unsigned b = __float_as_uint(bd);
    b = (b & 0x80000000u) ? ~b : (b | 0x80000000u);  // total-order transform
    unsigned long long key = ((unsigned long long)b << 32) | (unsigned)bj;
#pragma unroll
    for (int off = 1; off < 64; off <<= 1) {         // wave min-butterfly
      unsigned long long o = __shfl_xor(key, off);
      key = (o < key) ? o : key;
    }
    if (lane == 0) atomicMin(&sSlot[fpt], key);      // 8 atomics/point
  }
  __syncthreads();

  if (tid < PTS) {
    if (flagged) {
      bi = (int)(unsigned)(sSlot[tid] & 0xFFFFFFFFu);
      float4 cd = cw[bi];
      q0 = cd.x; q1 = cd.y; q2 = cd.z;
    }
    const int p = pbase + tid;
    // straight-through: t = q - x (f32), out = x + t (f32), like reference
    float t0 = q0 - x0, t1d = q1 - x1, t2d = q2 - x2;
    out_quant[3 * p + 0] = x0 + t0;
    out_quant[3 * p + 1] = x1 + t1d;
    out_quant[3 * p + 2] = x2 + t2d;
    out_idx[p] = (float)bi;
    sL[tid] = (double)t0 * t0 + (double)t1d * t1d + (double)t2d * t2d;
  }
  __syncthreads();

  if (tid == 0) {
    double acc = 0.0;
#pragma unroll 8
    for (int k = 0; k < PTS; ++k) acc += sL[k];
    // loss = mean((q-x)^2) + 0.25*mean((x-q)^2) = 1.25 * sum / (npts*3)
    atomicAdd(out_loss, (float)(acc * (1.25 / ((double)npts * 3.0))));
  }
}

extern "C" void kernel_launch(void* const* d_in, const int* in_sizes, int n_in,
                              void* d_out, int out_size, void* d_ws,
                              size_t ws_size, hipStream_t stream) {
  const float* feats = (const float*)d_in[0];      // (B*L, 3) f32
  const float* cb = (const float*)d_in[1];         // (4096, 3) f32
  const int npts = in_sizes[0] / 3;                // 65536

  float* out = (float*)d_out;
  float* out_quant = out;                          // npts*3 elems
  float* out_idx = out + in_sizes[0];              // npts elems
  float* out_loss = out + in_sizes[0] + npts;      // 1 elem

  float4* cw = (float4*)d_ws;                      // 4096 * 16 B = 64 KB

  vq_prep_kernel<<<VOCAB / 256, 256, 0, stream>>>(cb, cw, out_loss);
  vq_kernel<<<npts / PTS, 512, 0, stream>>>(feats, cw, out_quant, out_idx,
                                            out_loss, npts);
}

// Round 14
// 88.014 us; speedup vs baseline: 1.0817x; 1.0817x over previous
//
#include <hip/hip_runtime.h>

#define VOCAB 4096
#define SLICES 16
#define SLICE 256            // codes per slice (16-way split per point-set)
#define GRP 8                // codes per max-tree group
#define NGRP (SLICE / GRP)   // 32 groups per slice
#define P 4                  // points per lane
#define PTS (64 * P)         // 256 points per block
#define THREADS 1024

// Empty-asm register barrier: forces the value into a VGPR, preventing
// fma-contraction / reassociation across it. Emits no instruction.
__device__ __forceinline__ float opaque(float x) {
  asm volatile("" : "+v"(x));
  return x;
}

// v_max3_f32: value-identical to nested fmaxf for finite inputs (max is
// exact). Compiler won't form max3 without nnan, so emit directly.
__device__ __forceinline__ float max3f(float a, float b, float c) {
  float d;
  asm("v_max3_f32 %0, %1, %2, %3" : "=v"(d) : "v"(a), "v"(b), "v"(c));
  return d;
}

// Prep: pack per-code {e0, e1, e2, h} where h = -0.5f*c and
// c = ((e0*e0+e1*e1)+e2*e2) rounded exactly like numpy (each product/sum
// individually rounded f32). h is an exact scale of c (exponent shift),
// so c = -2*h is recoverable bit-exactly. (Validated R10/R12/R13.)
__global__ __launch_bounds__(256) void vq_prep_kernel(
    const float* __restrict__ cb, float4* __restrict__ cw,
    float* __restrict__ loss_slot) {
  int j = blockIdx.x * 256 + threadIdx.x;
  if (j == 0) *loss_slot = 0.0f;
  if (j < VOCAB) {
    float e0 = cb[3 * j + 0];
    float e1 = cb[3 * j + 1];
    float e2 = cb[3 * j + 2];
    float p0 = opaque(e0 * e0);
    float p1 = opaque(e1 * e1);
    float p2 = opaque(e2 * e2);
    float c = opaque(opaque(p0 + p1) + p2);
    cw[j] = make_float4(e0, e1, e2, -0.5f * c);
  }
}

// Surrogate scan value: t = x.e - c/2 (3 fma). Exact relation: a - 2T = D.
__device__ __forceinline__ float tval(float x0, float x1, float x2,
                                      float4 cd) {
  return fmaf(x0, cd.x, fmaf(x1, cd.y, fmaf(x2, cd.z, cd.w)));
}

// Bit-exact numpy f32 distance (validated absmax=0.0 R10/R12/R13):
//   m = x.e (fma ascending k, first term single-rounded mul)
//   d = (a - 2m) + c;  c = -2*h exact (fma-contract-safe).
__device__ __forceinline__ float dist_f32(float x0, float x1, float x2,
                                          float a, float4 cd) {
  float m = fmaf(x2, cd.z, fmaf(x1, cd.y, x0 * cd.x));
  return fmaf(-2.0f, m, a) + (-2.0f * cd.w);
}

// Main: 256 blocks x 1024 threads; block = 256 points (4/lane) x 16 slices.
// One block per CU: 16 waves/CU = 4/SIMD; LDS ~120 KB.
__global__ __launch_bounds__(THREADS) void vq_kernel(
    const float* __restrict__ feats, const float4* __restrict__ cw,
    float* __restrict__ out_quant, float* __restrict__ out_idx,
    float* __restrict__ out_loss, int npts) {
  __shared__ float4 sTab[VOCAB];            // 64 KB staged codebook
  __shared__ float sT1[SLICES * PTS];       // 16 KB per-slice best t
  __shared__ float sT2[SLICES * PTS];       // 16 KB per-slice 2nd-best
  __shared__ int sG[SLICES * PTS];          // 16 KB per-slice group base
  __shared__ unsigned long long sSlot[PTS]; // 2 KB fallback (d,idx) keys
  __shared__ int sList[PTS];                // 1 KB flagged point ids
  __shared__ int sCount;
  __shared__ double sL[PTS];                // 2 KB loss partials

  const int tid = threadIdx.x;
  const int lane = tid & 63;
  const int s = tid >> 6;                   // slice id 0..15 (wave-uniform)

  if (tid == 0) sCount = 0;

  // Stage codebook: coalesced float4 copy, 4 per thread.
#pragma unroll
  for (int k = 0; k < VOCAB / THREADS; ++k)
    sTab[tid + k * THREADS] = cw[tid + k * THREADS];

  const int pbase = blockIdx.x * PTS;
  // Lane's P points: pbase + k*64 + lane, k = 0..P-1 (same for all waves).
  float px[P], py[P], pz[P], nn[P];
#pragma unroll
  for (int k = 0; k < P; ++k) {
    const int p = pbase + k * 64 + lane;
    px[k] = feats[3 * p + 0];
    py[k] = feats[3 * p + 1];
    pz[k] = feats[3 * p + 2];
    // ||x||^2 exactly as numpy: products rounded, then ((p0+p1)+p2)
    float q0 = opaque(px[k] * px[k]);
    float q1 = opaque(py[k] * py[k]);
    float q2 = opaque(pz[k] * pz[k]);
    nn[k] = opaque(opaque(q0 + q1) + q2);
  }

  __syncthreads();  // staging complete

  const float4* cs = sTab + s * SLICE;

  // Phase 1: surrogate max-scan, P points per lane, codes via LDS broadcast.
  float t1[P], t2[P];
  int gg[P];
#pragma unroll
  for (int k = 0; k < P; ++k) { t1[k] = -3.4e38f; t2[k] = -3.4e38f; gg[k] = 0; }
#pragma unroll 2
  for (int g = 0; g < NGRP; ++g) {
    const float4* gp = cs + g * GRP;  // same addr all lanes -> broadcast
    float4 c0 = gp[0], c1 = gp[1], c2 = gp[2], c3 = gp[3];
    float4 c4 = gp[4], c5 = gp[5], c6 = gp[6], c7 = gp[7];
#pragma unroll
    for (int k = 0; k < P; ++k) {
      float u0 = tval(px[k], py[k], pz[k], c0);
      float u1 = tval(px[k], py[k], pz[k], c1);
      float u2 = tval(px[k], py[k], pz[k], c2);
      float u3 = tval(px[k], py[k], pz[k], c3);
      float u4 = tval(px[k], py[k], pz[k], c4);
      float u5 = tval(px[k], py[k], pz[k], c5);
      float u6 = tval(px[k], py[k], pz[k], c6);
      float u7 = tval(px[k], py[k], pz[k], c7);
      float gm = max3f(max3f(u0, u1, u2), max3f(u3, u4, u5), fmaxf(u6, u7));
      t2[k] = fmaxf(t2[k], fminf(t1[k], gm));  // streaming top-2
      if (gm > t1[k]) gg[k] = g;               // strict >: earliest group
      t1[k] = fmaxf(t1[k], gm);
    }
  }
#pragma unroll
  for (int k = 0; k < P; ++k) {
    sT1[s * PTS + k * 64 + lane] = t1[k];
    sT2[s * PTS + k * 64 + lane] = t2[k];
    sG[s * PTS + k * 64 + lane] = s * SLICE + gg[k] * GRP;
  }
  __syncthreads();

  // Epilogue combine: tid < 256 owns block-point pt == tid; its coords are
  // its own registers' point k == s (waves 0..3 cover tid 0..255).
  int bi = 0;
  float q0 = 0.0f, q1 = 0.0f, q2 = 0.0f;
  bool flagged = false;
  float x0 = px[0], x1 = py[0], x2 = pz[0], a = nn[0];
#pragma unroll
  for (int k = 1; k < P; ++k) {
    if (s == k) { x0 = px[k]; x1 = py[k]; x2 = pz[k]; a = nn[k]; }
  }
  if (tid < PTS) {
    float b1 = sT1[tid], b2 = sT2[tid];
    int gbase = sG[tid];
#pragma unroll
    for (int k = 1; k < SLICES; ++k) {  // ascending slice order
      float u1 = sT1[k * PTS + tid];
      float u2 = sT2[k * PTS + tid];
      b2 = fmaxf(fmaxf(b2, u2), fminf(b1, u1));
      if (u1 > b1) gbase = sG[k * PTS + tid];
      b1 = fmaxf(b1, u1);
    }
    // Margin test (validated R10/R12/R13): if best group's t beats every
    // other group's max by more than worst-case surrogate-vs-numpy skew,
    // ref argmin is inside gbase. eps = a*2^-21 + 2^-20 (2x safe).
    float eps = fmaf(a, 0x1p-21f, 0x1p-20f);
    flagged = !((b1 - b2) > eps);
    if (flagged) {
      int pos = atomicAdd(&sCount, 1);
      sList[pos] = tid;
      sSlot[tid] = ~0ULL;
    } else {
      // Bit-exact rescan of the certified 8-code group (from LDS copy);
      // ascending, strict <: np.argmin first-occurrence.
      float bd = 3.4e38f;
#pragma unroll
      for (int k = 0; k < GRP; ++k) {
        float4 cd = sTab[gbase + k];
        float d = dist_f32(x0, x1, x2, a, cd);
        if (d < bd) { bd = d; bi = gbase + k; q0 = cd.x; q1 = cd.y; q2 = cd.z; }
      }
    }
  }
  __syncthreads();

  // Phase 2: cooperative bit-exact full rescan for flagged points.
  // 1024 threads x 4 codes each; sortable (d,idx) key min-reduce: min key
  // == min d, tie -> min idx (first occurrence).
  const int cnt = sCount;
  for (int f = 0; f < cnt; ++f) {
    const int fpt = sList[f];
    const int fp = pbase + fpt;
    float y0 = feats[3 * fp + 0];   // same addr all threads -> broadcast
    float y1 = feats[3 * fp + 1];
    float y2 = feats[3 * fp + 2];
    float yp0 = opaque(y0 * y0);
    float yp1 = opaque(y1 * y1);
    float yp2 = opaque(y2 * y2);
    float ay = opaque(opaque(yp0 + yp1) + yp2);
    float bd = 3.4e38f;
    int bj = 0;
#pragma unroll
    for (int k = 0; k < VOCAB / THREADS; ++k) {
      int j = tid + k * THREADS;
      float4 cd = sTab[j];
      float d = dist_f32(y0, y1, y2, ay, cd);
      if (d < bd) { bd = d; bj = j; }
    }
    unsigned b = __float_as_uint(bd);
    b = (b & 0x80000000u) ? ~b : (b | 0x80000000u);  // total-order transform
    unsigned long long key = ((unsigned long long)b << 32) | (unsigned)bj;
#pragma unroll
    for (int off = 1; off < 64; off <<= 1) {         // wave min-butterfly
      unsigned long long o = __shfl_xor(key, off);
      key = (o < key) ? o : key;
    }
    if (lane == 0) atomicMin(&sSlot[fpt], key);      // 16 atomics/point
  }
  __syncthreads();

  if (tid < PTS) {
    if (flagged) {
      bi = (int)(unsigned)(sSlot[tid] & 0xFFFFFFFFu);
      float4 cd = sTab[bi];
      q0 = cd.x; q1 = cd.y; q2 = cd.z;
    }
    const int p = pbase + tid;
    // straight-through: t = q - x (f32), out = x + t (f32), like reference
    float t0 = q0 - x0, t1d = q1 - x1, t2d = q2 - x2;
    out_quant[3 * p + 0] = x0 + t0;
    out_quant[3 * p + 1] = x1 + t1d;
    out_quant[3 * p + 2] = x2 + t2d;
    out_idx[p] = (float)bi;
    sL[tid] = (double)t0 * t0 + (double)t1d * t1d + (double)t2d * t2d;
  }
  __syncthreads();

  if (tid == 0) {
    double acc = 0.0;
#pragma unroll 8
    for (int k = 0; k < PTS; ++k) acc += sL[k];
    // loss = mean((q-x)^2) + 0.25*mean((x-q)^2) = 1.25 * sum / (npts*3)
    atomicAdd(out_loss, (float)(acc * (1.25 / ((double)npts * 3.0))));
  }
}

extern "C" void kernel_launch(void* const* d_in, const int* in_sizes, int n_in,
                              void* d_out, int out_size, void* d_ws,
                              size_t ws_size, hipStream_t stream) {
  const float* feats = (const float*)d_in[0];      // (B*L, 3) f32
  const float* cb = (const float*)d_in[1];         // (4096, 3) f32
  const int npts = in_sizes[0] / 3;                // 65536

  float* out = (float*)d_out;
  float* out_quant = out;                          // npts*3 elems
  float* out_idx = out + in_sizes[0];              // npts elems
  float* out_loss = out + in_sizes[0] + npts;      // 1 elem

  float4* cw = (float4*)d_ws;                      // 4096 * 16 B = 64 KB

  vq_prep_kernel<<<VOCAB / 256, 256, 0, stream>>>(cb, cw, out_loss);
  vq_kernel<<<npts / PTS, THREADS, 0, stream>>>(feats, cw, out_quant, out_idx,
                                                out_loss, npts);
}